// Round 23
// baseline (229.431 us; speedup 1.0000x reference)
//
#include <hip/hip_runtime.h>
#include <hip/hip_fp16.h>
#include <math.h>

// MPS-RNN 2D forward: L=8, M=8, DCUT=6, HL=2, N=64, B=32768
// Round-23: 1 lane = 1 sample. All params are wave-uniform -> scalar (s_load)
// pipe via a snake-ordered repacked ws image. No DPP tail (norm/prob/select
// lane-local), no barriers, LDS only for per-lane vertical state (3 b32
// planes, conflict-free, self-ordered). 512 waves of dense dot2 chains.
// Fallback to r16-style kernel if ws too small.

#define NQ  64
#define BT  64
#define SLOT_U 312   // per-step image: 288 T/M | 12 vv | 6 e2 | 3 W | 1 C | pad
#define WS_NEED (64 * SLOT_U * 4)

typedef _Float16 h2v __attribute__((ext_vector_type(2)));
typedef __fp16  p2v __attribute__((ext_vector_type(2)));
union H2U { unsigned u; h2v h; __half2 hh; };

static __device__ __forceinline__ h2v pack2(float a, float b) {
    p2v p = __builtin_amdgcn_cvt_pkrtz(a, b);
    h2v r; __builtin_memcpy(&r, &p, sizeof(r));
    return r;
}
static __device__ __forceinline__ h2v u2h(unsigned u) {
    h2v r; __builtin_memcpy(&r, &u, sizeof(r));
    return r;
}
static __device__ __forceinline__ unsigned h2u(h2v h) {
    unsigned r; __builtin_memcpy(&r, &h, sizeof(r));
    return r;
}

#define DPPF(x, ctrl) __int_as_float(__builtin_amdgcn_update_dpp(            \
    __float_as_int(x), __float_as_int(x), (ctrl), 0xF, 0xF, false))
#define QP_XOR1 0xB1
#define QP_XOR2 0x4E
#define QP_BC0  0x00
#define QP_BC1  0x55

#if defined(__has_builtin)
#  if __has_builtin(__builtin_amdgcn_rcpf)
#    define FAST_RCP(x) __builtin_amdgcn_rcpf(x)
#  else
#    define FAST_RCP(x) (1.0f / (x))
#  endif
#  if __has_builtin(__builtin_amdgcn_rsqf)
#    define FAST_RSQ(x) __builtin_amdgcn_rsqf(x)
#  else
#    define FAST_RSQ(x) rsqrtf(x)
#  endif
#  if __has_builtin(__builtin_amdgcn_fdot2)
#    define HAS_FDOT2 1
#  endif
#else
#  define FAST_RCP(x) (1.0f / (x))
#  define FAST_RSQ(x) rsqrtf(x)
#endif

static __device__ __forceinline__ float fdot2u(unsigned a, h2v b, float c) {
#ifdef HAS_FDOT2
    H2U u; u.u = a;
    return __builtin_amdgcn_fdot2(u.h, b, c, false);
#else
    H2U u; u.u = a;
    return fmaf((float)u.h.x, (float)b.x, fmaf((float)u.h.y, (float)b.y, c));
#endif
}

// ---------- one-time param repack into snake-step order (grid 64) -----------
__global__ void repack23(
    const float* __restrict__ Mh, const float* __restrict__ Mv,
    const float* __restrict__ Vp, const float* __restrict__ Tp,
    const float* __restrict__ Wp, const float* __restrict__ Cp,
    const float* __restrict__ Ep, unsigned* __restrict__ ws)
{
    const int k = blockIdx.x;          // snake step index
    const int t = threadIdx.x;
    const int i = k >> 3, jm = k & 7;
    const int j = (i & 1) ? 7 - jm : jm;
    const int site = i * 8 + j;
    unsigned* S = ws + k * SLOT_U;
    float*    F = reinterpret_cast<float*>(S + 288);

    const float2* gT = reinterpret_cast<const float2*>(Tp + site * 432);
    for (int p = t; p < 216; p += BT) {
        int row = p / 18, w = p - row * 18;
        float2 v = gT[p];
        H2U hu; hu.hh = __floats2half2_rn(v.x, v.y);
        S[row * 24 + w] = hu.u;
    }
    const float2* gH = reinterpret_cast<const float2*>(Mh + site * 72);
    const float2* gV = reinterpret_cast<const float2*>(Mv + site * 72);
    if (t < 36) {
        int row = t / 3, w = t - row * 3;
        int o_r = row - ((row >= 6) ? 6 : 0);    // row % 6
        float2 vh = gH[t], vv2 = gV[t];
        if ((o_r >> 1) == w) {                   // residual diag fold (+1)
            if (o_r & 1) { vh.y += 1.f; vv2.y += 1.f; }
            else         { vh.x += 1.f; vv2.x += 1.f; }
        }
        H2U a; a.hh = __floats2half2_rn(vh.x, vh.y);
        H2U c; c.hh = __floats2half2_rn(vv2.x, vv2.y);
        S[row * 24 + 18 + w] = a.u;
        S[row * 24 + 21 + w] = c.u;
    } else if (t < 48) {
        F[t - 36] = Vp[site * 12 + (t - 36)];    // vv[12]
    } else if (t < 54) {
        float e = Ep[site * 6 + (t - 48)];
        F[12 + (t - 48)] = e * e;                // e2[6]
    } else if (t < 57) {
        const float2* gw = reinterpret_cast<const float2*>(Wp + site * 6);
        float2 wp = gw[t - 54];
        H2U u; u.hh = __floats2half2_rn(wp.x, wp.y);
        S[306 + (t - 54)] = u.u;                 // W packed [3]
    } else if (t == 57) {
        F[21] = Cp[site];                        // C
    }
}

// ---------- main kernel: 1 lane per sample ----------------------------------
__global__ __launch_bounds__(BT) void mps_rnn23(
    const unsigned* __restrict__ ws,
    const int* __restrict__ X,
    float* __restrict__ out, int Bn, int writeImag)
{
    __shared__ unsigned v0[512], v1[512], v2[512];   // [j*64 + lane]

    const int lane = threadIdx.x;
    int b = blockIdx.x * BT + lane;
    const bool valid = (b < Bn);
    if (!valid) b = Bn - 1;

    // per-lane occupation bits (own sample; one-time scattered read)
    unsigned long long bits = 0ull;
    {
        const int4* xr = reinterpret_cast<const int4*>(X + (size_t)b * NQ);
        #pragma unroll
        for (int q = 0; q < 16; ++q) {
            int4 v = xr[q];
            bits |= (unsigned long long)(v.x & 1) << (4 * q + 0);
            bits |= (unsigned long long)(v.y & 1) << (4 * q + 1);
            bits |= (unsigned long long)(v.z & 1) << (4 * q + 2);
            bits |= (unsigned long long)(v.w & 1) << (4 * q + 3);
        }
    }

    // vertical state zero (each lane owns slots lane+64j; no sync needed)
    #pragma unroll
    for (int jj = 0; jj < 8; ++jj) {
        v0[jj * 64 + lane] = 0u;
        v1[jj * 64 + lane] = 0u;
        v2[jj * 64 + lane] = 0u;
    }

    float hh[6];
    h2v hhp0, hhp1, hhp2;
    float amp2 = 1.f, phi = 0.f;

    #pragma unroll 2
    for (int k = 0; k < NQ; ++k) {
        const int jm  = k & 7;
        const int dir = (k >> 3) & 1;
        const int j   = dir ? 7 - jm : jm;
        const unsigned* P = ws + k * SLOT_U;        // uniform -> scalar loads
        const float*    F = reinterpret_cast<const float*>(P + 288);

        if (jm == 0) {                              // left boundary
            #pragma unroll
            for (int o = 0; o < 6; ++o) hh[o] = 1.f;
            H2U one; one.u = 0x3C003C00u;
            hhp0 = one.h; hhp1 = one.h; hhp2 = one.h;
        }

        const int vi = j * 64 + lane;
        const h2v hv0 = u2h(v0[vi]);
        const h2v hv1 = u2h(v1[vi]);
        const h2v hv2 = u2h(v2[vi]);

        float h[12];
        #pragma unroll
        for (int r = 0; r < 12; ++r) {
            const unsigned* R = P + r * 24;         // uniform row base
            float sc0 = fdot2u(R[0],  hv0, fdot2u(R[1],  hv1, fdot2u(R[2],  hv2, 0.f)));
            float sc1 = fdot2u(R[3],  hv0, fdot2u(R[4],  hv1, fdot2u(R[5],  hv2, 0.f)));
            float sc2 = fdot2u(R[6],  hv0, fdot2u(R[7],  hv1, fdot2u(R[8],  hv2, 0.f)));
            float sc3 = fdot2u(R[9],  hv0, fdot2u(R[10], hv1, fdot2u(R[11], hv2, 0.f)));
            float sc4 = fdot2u(R[12], hv0, fdot2u(R[13], hv1, fdot2u(R[14], hv2, 0.f)));
            float sc5 = fdot2u(R[15], hv0, fdot2u(R[16], hv1, fdot2u(R[17], hv2, 0.f)));
            float ta = fmaf(sc0, hh[0], fmaf(sc2, hh[2], sc4 * hh[4]));
            float tb = fmaf(sc1, hh[1], fmaf(sc3, hh[3], sc5 * hh[5]));
            float md = fdot2u(R[18], hhp0, fdot2u(R[19], hhp1,
                       fdot2u(R[20], hhp2, F[r])));          // diag-folded + V seed
            float nd = fdot2u(R[21], hv0, fdot2u(R[22], hv1,
                       fdot2u(R[23], hv2, 0.f)));            // diag-folded
            h[r] = (ta + tb) + (md + nd);
        }

        // lane-local tail: norm, prob, select, phase
        float hsq[12];
        #pragma unroll
        for (int r = 0; r < 12; ++r) hsq[r] = h[r] * h[r];
        float sA = (hsq[0] + hsq[1]) + (hsq[2] + hsq[3]);
        float sB = (hsq[4] + hsq[5]) + (hsq[6] + hsq[7]);
        float sC = (hsq[8] + hsq[9]) + (hsq[10] + hsq[11]);
        const float ss = (sA + sB) + sC;
        float q0 = fmaf(F[12], hsq[0], fmaf(F[13], hsq[1], fmaf(F[14], hsq[2],
                   fmaf(F[15], hsq[3], fmaf(F[16], hsq[4], F[17] * hsq[5])))));
        float q1 = fmaf(F[12], hsq[6], fmaf(F[13], hsq[7], fmaf(F[14], hsq[8],
                   fmaf(F[15], hsq[9], fmaf(F[16], hsq[10], F[17] * hsq[11])))));
        const float inv = FAST_RSQ(ss + 1e-12f);

        const int sel = (int)((bits >> k) & 1ull);
        const float psel = sel ? q1 : q0;
        amp2 *= psel * FAST_RCP(q0 + q1);

        #pragma unroll
        for (int o = 0; o < 6; ++o)
            hh[o] = (sel ? h[6 + o] : h[o]) * inv;
        hhp0 = pack2(hh[0], hh[1]);
        hhp1 = pack2(hh[2], hh[3]);
        hhp2 = pack2(hh[4], hh[5]);

        phi = fdot2u(P[306], hhp0, fdot2u(P[307], hhp1,
              fdot2u(P[308], hhp2, F[21] + phi)));

        v0[vi] = h2u(hhp0);
        v1[vi] = h2u(hhp1);
        v2[vi] = h2u(hhp2);
    }

    if (valid) {
        const float amp = sqrtf(amp2);
        if (writeImag) {
            out[2 * b + 0] = amp * cosf(phi);
            out[2 * b + 1] = amp * sinf(phi);
        } else {
            out[b] = amp * cosf(phi);
        }
    }
}

// ---------- fallback: r16-style kernel (in-kernel staging, 4 lanes/sample) --
__global__ __launch_bounds__(256, 1) void mps_rnn16fb(
    const float* __restrict__ Mh, const float* __restrict__ Mv,
    const float* __restrict__ Vp, const float* __restrict__ Tp,
    const float* __restrict__ Wp, const float* __restrict__ Cp,
    const float* __restrict__ Ep, const int* __restrict__ X,
    float* __restrict__ out, int Bn, int writeImag)
{
    __shared__ unsigned Tl[16 * 12 * 24];
    __shared__ float    VE [16 * 4 * 8];
    __shared__ uint4    Wl [16];
    __shared__ unsigned vsm[8 * 64 * 4];

    const int t   = threadIdx.x;
    const int sub = t & 3;
    const int s   = t >> 2;
    int b = blockIdx.x * 64 + s;
    const bool valid = (b < Bn);
    if (!valid) b = Bn - 1;

    unsigned long long bits;
    {
        const int4* xr = reinterpret_cast<const int4*>(X + (size_t)b * NQ + sub * 16);
        unsigned long long part = 0ull;
        #pragma unroll
        for (int q = 0; q < 4; ++q) {
            int4 v = xr[q];
            part |= (unsigned long long)(v.x & 1) << (4 * q + 0);
            part |= (unsigned long long)(v.y & 1) << (4 * q + 1);
            part |= (unsigned long long)(v.z & 1) << (4 * q + 2);
            part |= (unsigned long long)(v.w & 1) << (4 * q + 3);
        }
        bits = part << (16 * sub);
        bits |= __shfl_xor(bits, 1, 64);
        bits |= __shfl_xor(bits, 2, 64);
    }
    for (int u = t; u < 8 * 64 * 4; u += 256) vsm[u] = 0u;
    const int mya = sub >> 1;
    float hh[6];
    h2v hhp0, hhp1, hhp2;
    float amp2 = 1.f, phi = 0.f;

    for (int ch = 0; ch < 4; ++ch) {
        __syncthreads();
        {
            const float2* gT = reinterpret_cast<const float2*>(Tp + ch * 6912);
            for (int p = t; p < 3456; p += 256) {
                int site = p / 216, rr = p - site * 216;
                int row = rr / 18,  w  = rr - row * 18;
                float2 v = gT[p];
                H2U hu; hu.hh = __floats2half2_rn(v.x, v.y);
                Tl[(site * 12 + row) * 24 + w] = hu.u;
            }
            const float2* gH = reinterpret_cast<const float2*>(Mh + ch * 1152);
            const float2* gV = reinterpret_cast<const float2*>(Mv + ch * 1152);
            for (int p = t; p < 576; p += 256) {
                int site = p / 36, rr = p - site * 36;
                int row = rr / 3,  w  = rr - row * 3;
                int o_r = row - ((row >= 6) ? 6 : 0);
                float2 vh = gH[p], vv2 = gV[p];
                if ((o_r >> 1) == w) {
                    if (o_r & 1) { vh.y += 1.f; vv2.y += 1.f; }
                    else         { vh.x += 1.f; vv2.x += 1.f; }
                }
                H2U a; a.hh = __floats2half2_rn(vh.x, vh.y);
                H2U c; c.hh = __floats2half2_rn(vv2.x, vv2.y);
                Tl[(site * 12 + row) * 24 + 18 + w] = a.u;
                Tl[(site * 12 + row) * 24 + 21 + w] = c.u;
            }
            if (t < 192) {
                int site = t / 12, q = t - site * 12;
                int sb = q / 3,    c = q - sb * 3;
                VE[(site * 4 + sb) * 8 + c] = Vp[ch * 192 + t];
                float e = Ep[ch * 96 + site * 6 + (sb & 1) * 3 + c];
                VE[(site * 4 + sb) * 8 + 3 + c] = e * e;
            } else if (t < 208) {
                int site = t - 192;
                const float2* gw = reinterpret_cast<const float2*>(Wp) + ch * 48 + site * 3;
                float2 w01 = gw[0], w23 = gw[1], w45 = gw[2];
                H2U u0, u1, u2;
                u0.hh = __floats2half2_rn(w01.x, w01.y);
                u1.hh = __floats2half2_rn(w23.x, w23.y);
                u2.hh = __floats2half2_rn(w45.x, w45.y);
                Wl[site] = make_uint4(u0.u, u1.u, u2.u,
                                      __float_as_uint(Cp[ch * 16 + site]));
            }
        }
        __syncthreads();

        #pragma unroll
        for (int ih = 0; ih < 2; ++ih) {
            const unsigned cbr = (unsigned)(bits >> (ch * 16 + ih * 8)) & 0xFFu;
            #pragma unroll 2
            for (int qq = 0; qq < 8; ++qq) {
                const int j    = ih ? 7 - qq : qq;
                const int slot = ih * 8 + j;
                const unsigned* Tb = Tl + (slot * 12 + sub * 3) * 24;
                const float*   VEb = VE + (slot * 4 + sub) * 8;
                if (qq == 0) {
                    #pragma unroll
                    for (int o = 0; o < 6; ++o) hh[o] = 1.f;
                    H2U one; one.u = 0x3C003C00u;
                    hhp0 = one.h; hhp1 = one.h; hhp2 = one.h;
                }
                uint4 hvu = *reinterpret_cast<const uint4*>(vsm + j * 256 + s * 4);
                const h2v hvh0 = u2h(hvu.x);
                const h2v hvh1 = u2h(hvu.y);
                const h2v hvh2 = u2h(hvu.z);
                float4 ve0 = *reinterpret_cast<const float4*>(VEb);
                float2 ve1 = *reinterpret_cast<const float2*>(VEb + 4);
                const float vv_[3] = { ve0.x, ve0.y, ve0.z };
                const float e2_[3] = { ve0.w, ve1.x, ve1.y };
                float acc[3];
                #pragma unroll
                for (int lr = 0; lr < 3; ++lr) {
                    const unsigned* Tr = Tb + lr * 24;
                    uint4 tA = *reinterpret_cast<const uint4*>(Tr);
                    uint4 tB = *reinterpret_cast<const uint4*>(Tr + 4);
                    uint4 tC = *reinterpret_cast<const uint4*>(Tr + 8);
                    uint4 tD = *reinterpret_cast<const uint4*>(Tr + 12);
                    uint4 tE = *reinterpret_cast<const uint4*>(Tr + 16);
                    uint4 tF = *reinterpret_cast<const uint4*>(Tr + 20);
                    const unsigned tw[18] = {tA.x,tA.y,tA.z,tA.w, tB.x,tB.y,tB.z,tB.w,
                                             tC.x,tC.y,tC.z,tC.w, tD.x,tD.y,tD.z,tD.w,
                                             tE.x,tE.y};
                    float sc[6];
                    #pragma unroll
                    for (int c = 0; c < 6; ++c)
                        sc[c] = fdot2u(tw[c*3+0], hvh0,
                                fdot2u(tw[c*3+1], hvh1,
                                fdot2u(tw[c*3+2], hvh2, 0.f)));
                    float ta = fmaf(sc[0], hh[0], fmaf(sc[2], hh[2], sc[4]*hh[4]));
                    float tb = fmaf(sc[1], hh[1], fmaf(sc[3], hh[3], sc[5]*hh[5]));
                    float md = fdot2u(tE.z, hhp0, fdot2u(tE.w, hhp1,
                               fdot2u(tF.x, hhp2, vv_[lr])));
                    float nd = fdot2u(tF.y, hvh0, fdot2u(tF.z, hvh1,
                               fdot2u(tF.w, hvh2, 0.f)));
                    acc[lr] = (ta + tb) + (md + nd);
                }
                float q0_ = acc[0]*acc[0], q1_ = acc[1]*acc[1], q2_ = acc[2]*acc[2];
                float ssl = (q0_ + q1_) + q2_;
                float pq  = fmaf(e2_[0], q0_, fmaf(e2_[1], q1_, e2_[2] * q2_));
                float s1  = ssl + DPPF(ssl, QP_XOR1);
                float ssq = s1 + DPPF(s1, QP_XOR2);
                float p1  = pq + DPPF(pq, QP_XOR1);
                float px  = DPPF(p1, QP_XOR2);
                const float inv = FAST_RSQ(ssq + 1e-12f);
                const int sel = (cbr >> qq) & 1;
                const float qsel = (mya == sel) ? p1 : px;
                amp2 *= qsel * FAST_RCP(p1 + px);
                float an0 = acc[0] * inv, an1 = acc[1] * inv, an2 = acc[2] * inv;
                float sw0 = DPPF(an0, QP_XOR2);
                float sw1 = DPPF(an1, QP_XOR2);
                float sw2 = DPPF(an2, QP_XOR2);
                an0 = sel ? sw0 : an0;
                an1 = sel ? sw1 : an1;
                an2 = sel ? sw2 : an2;
                hh[0] = DPPF(an0, QP_BC0); hh[3] = DPPF(an0, QP_BC1);
                hh[1] = DPPF(an1, QP_BC0); hh[4] = DPPF(an1, QP_BC1);
                hh[2] = DPPF(an2, QP_BC0); hh[5] = DPPF(an2, QP_BC1);
                hhp0 = pack2(hh[0], hh[1]);
                hhp1 = pack2(hh[2], hh[3]);
                hhp2 = pack2(hh[4], hh[5]);
                uint4 wv = Wl[slot];
                phi = fdot2u(wv.x, hhp0, fdot2u(wv.y, hhp1,
                      fdot2u(wv.z, hhp2, __uint_as_float(wv.w) + phi)));
                if (sub == 0) {
                    *reinterpret_cast<uint4*>(vsm + j * 256 + s * 4) =
                        make_uint4(h2u(hhp0), h2u(hhp1), h2u(hhp2), 0u);
                }
            }
        }
    }

    if (sub == 0 && valid) {
        const float amp = sqrtf(amp2);
        if (writeImag) {
            out[2 * b + 0] = amp * cosf(phi);
            out[2 * b + 1] = amp * sinf(phi);
        } else {
            out[b] = amp * cosf(phi);
        }
    }
}

extern "C" void kernel_launch(void* const* d_in, const int* in_sizes, int n_in,
                              void* d_out, int out_size, void* d_ws, size_t ws_size,
                              hipStream_t stream) {
    const float* Mh = (const float*)d_in[0];
    const float* Mv = (const float*)d_in[1];
    const float* Vp = (const float*)d_in[2];
    const float* Tp = (const float*)d_in[3];
    const float* Wp = (const float*)d_in[4];
    const float* Cp = (const float*)d_in[5];
    const float* Ep = (const float*)d_in[6];
    const int*   X  = (const int*)d_in[7];
    float* out = (float*)d_out;

    const int Bn = in_sizes[7] / NQ;                 // 32768
    const int writeImag = (out_size >= 2 * Bn) ? 1 : 0;

    if (ws_size >= (size_t)WS_NEED) {
        repack23<<<64, BT, 0, stream>>>(Mh, Mv, Vp, Tp, Wp, Cp, Ep,
                                        (unsigned*)d_ws);
        const int grid = (Bn + BT - 1) / BT;         // 512 blocks of 64
        mps_rnn23<<<grid, BT, 0, stream>>>((const unsigned*)d_ws, X, out,
                                           Bn, writeImag);
    } else {
        const int grid = (Bn + 63) / 64;
        mps_rnn16fb<<<grid, 256, 0, stream>>>(Mh, Mv, Vp, Tp, Wp, Cp, Ep, X,
                                              out, Bn, writeImag);
    }
}

// Round 24
// 63.363 us; speedup vs baseline: 3.6209x; 3.6209x over previous
//
#include <hip/hip_runtime.h>
#include <hip/hip_fp16.h>
#include <math.h>

// MPS-RNN 2D forward: L=8, M=8, DCUT=6, HL=2, N=64, B=32768
// Round-24 = round-20 restored verbatim (63.3us, the measured optimum).
// Structure: 4 lanes/sample, SPB=64, 16-site LDS chunks from a prebuilt
// ws image (repack kernel), fp16 dot2 for T/Mh/Mv/W, DPP cross-lane,
// diag-folded residuals, row-boundary bypass, packed-fp16 vertical state.
// Seven structural alternatives (r15,r17,r18,r19,r21,r22,r23) all regress.

#define NQ  64
#define BT  256
#define SPB 64
#define CHUNK_U 5184   // uints per chunk image: 4608 T/M | 512 VE(f32) | 64 Wl

typedef _Float16 h2v __attribute__((ext_vector_type(2)));
typedef __fp16  p2v __attribute__((ext_vector_type(2)));
union H2U { unsigned u; h2v h; __half2 hh; };

static __device__ __forceinline__ h2v pack2(float a, float b) {
    p2v p = __builtin_amdgcn_cvt_pkrtz(a, b);
    h2v r; __builtin_memcpy(&r, &p, sizeof(r));
    return r;
}
static __device__ __forceinline__ h2v u2h(unsigned u) {
    h2v r; __builtin_memcpy(&r, &u, sizeof(r));
    return r;
}
static __device__ __forceinline__ unsigned h2u(h2v h) {
    unsigned r; __builtin_memcpy(&r, &h, sizeof(r));
    return r;
}

#define DPPF(x, ctrl) __int_as_float(__builtin_amdgcn_update_dpp(            \
    __float_as_int(x), __float_as_int(x), (ctrl), 0xF, 0xF, false))
#define QP_XOR1 0xB1
#define QP_XOR2 0x4E
#define QP_BC0  0x00
#define QP_BC1  0x55

#if defined(__has_builtin)
#  if __has_builtin(__builtin_amdgcn_rcpf)
#    define FAST_RCP(x) __builtin_amdgcn_rcpf(x)
#  else
#    define FAST_RCP(x) (1.0f / (x))
#  endif
#  if __has_builtin(__builtin_amdgcn_rsqf)
#    define FAST_RSQ(x) __builtin_amdgcn_rsqf(x)
#  else
#    define FAST_RSQ(x) rsqrtf(x)
#  endif
#  if __has_builtin(__builtin_amdgcn_fdot2)
#    define HAS_FDOT2 1
#  endif
#else
#  define FAST_RCP(x) (1.0f / (x))
#  define FAST_RSQ(x) rsqrtf(x)
#endif

static __device__ __forceinline__ float fdot2u(unsigned a, h2v b, float c) {
#ifdef HAS_FDOT2
    H2U u; u.u = a;
    return __builtin_amdgcn_fdot2(u.h, b, c, false);
#else
    H2U u; u.u = a;
    return fmaf((float)u.h.x, (float)b.x, fmaf((float)u.h.y, (float)b.y, c));
#endif
}

// ---------- one-time param repack (grid 4 = one block per 16-site chunk) ----
__global__ void repack_k(
    const float* __restrict__ Mh, const float* __restrict__ Mv,
    const float* __restrict__ Vp, const float* __restrict__ Tp,
    const float* __restrict__ Wp, const float* __restrict__ Cp,
    const float* __restrict__ Ep, unsigned* __restrict__ ws)
{
    const int ch = blockIdx.x;
    const int t  = threadIdx.x;
    unsigned* Tm = ws + ch * CHUNK_U;
    float*    VE = reinterpret_cast<float*>(Tm + 4608);
    uint4*    Wl = reinterpret_cast<uint4*>(Tm + 4608 + 512);

    const float2* gT = reinterpret_cast<const float2*>(Tp + ch * 6912);
    for (int p = t; p < 3456; p += BT) {
        int site = p / 216, rr = p - site * 216;
        int row = rr / 18,  w  = rr - row * 18;
        float2 v = gT[p];
        H2U hu; hu.hh = __floats2half2_rn(v.x, v.y);
        Tm[(site * 12 + row) * 24 + w] = hu.u;
    }
    const float2* gH = reinterpret_cast<const float2*>(Mh + ch * 1152);
    const float2* gV = reinterpret_cast<const float2*>(Mv + ch * 1152);
    for (int p = t; p < 576; p += BT) {
        int site = p / 36, rr = p - site * 36;
        int row = rr / 3,  w  = rr - row * 3;
        int o_r = row - ((row >= 6) ? 6 : 0);     // row % 6
        float2 vh = gH[p], vv2 = gV[p];
        if ((o_r >> 1) == w) {                    // residual diag fold (+1)
            if (o_r & 1) { vh.y += 1.f; vv2.y += 1.f; }
            else         { vh.x += 1.f; vv2.x += 1.f; }
        }
        H2U a; a.hh = __floats2half2_rn(vh.x, vh.y);
        H2U c; c.hh = __floats2half2_rn(vv2.x, vv2.y);
        Tm[(site * 12 + row) * 24 + 18 + w] = a.u;
        Tm[(site * 12 + row) * 24 + 21 + w] = c.u;
    }
    if (t < 192) {
        int site = t / 12, q = t - site * 12;
        int sb = q / 3,    c = q - sb * 3;
        VE[(site * 4 + sb) * 8 + c] = Vp[ch * 192 + t];
        float e = Ep[ch * 96 + site * 6 + (sb & 1) * 3 + c];
        VE[(site * 4 + sb) * 8 + 3 + c] = e * e;
    } else if (t < 208) {
        int site = t - 192;
        const float2* gw = reinterpret_cast<const float2*>(Wp) + ch * 48 + site * 3;
        float2 w01 = gw[0], w23 = gw[1], w45 = gw[2];
        H2U u0, u1, u2;
        u0.hh = __floats2half2_rn(w01.x, w01.y);
        u1.hh = __floats2half2_rn(w23.x, w23.y);
        u2.hh = __floats2half2_rn(w45.x, w45.y);
        Wl[site] = make_uint4(u0.u, u1.u, u2.u,
                              __float_as_uint(Cp[ch * 16 + site]));
    }
}

// ---------- main kernel (ws-staged) -----------------------------------------
__global__ __launch_bounds__(BT, 1) void mps_rnn24(
    const unsigned* __restrict__ ws,
    const int* __restrict__ X,
    float* __restrict__ out, int Bn, int writeImag)
{
    __shared__ uint4    ldsb[CHUNK_U / 4];   // 20736 B chunk image
    __shared__ unsigned vsm[8 * 64 * 4];     // 8192 B vertical state (packed fp16)

    unsigned*     Tl = reinterpret_cast<unsigned*>(ldsb);
    const float*  VE = reinterpret_cast<const float*>(Tl + 4608);
    const uint4*  Wl = reinterpret_cast<const uint4*>(Tl + 4608 + 512);

    const int t   = threadIdx.x;
    const int sub = t & 3;
    const int s   = t >> 2;
    int b = blockIdx.x * SPB + s;
    const bool valid = (b < Bn);
    if (!valid) b = Bn - 1;          // clamp loads; no early return (barriers!)

    unsigned long long bits;
    {
        const int4* xr = reinterpret_cast<const int4*>(X + (size_t)b * NQ + sub * 16);
        unsigned long long part = 0ull;
        #pragma unroll
        for (int q = 0; q < 4; ++q) {
            int4 v = xr[q];
            part |= (unsigned long long)(v.x & 1) << (4 * q + 0);
            part |= (unsigned long long)(v.y & 1) << (4 * q + 1);
            part |= (unsigned long long)(v.z & 1) << (4 * q + 2);
            part |= (unsigned long long)(v.w & 1) << (4 * q + 3);
        }
        bits = part << (16 * sub);
        bits |= __shfl_xor(bits, 1, 64);
        bits |= __shfl_xor(bits, 2, 64);
    }

    for (int u = t; u < 8 * 64 * 4; u += BT) vsm[u] = 0u;

    const int mya = sub >> 1;

    float hh[6];
    h2v hhp0, hhp1, hhp2;
    float amp2 = 1.f, phi = 0.f;

    for (int ch = 0; ch < 4; ++ch) {
        __syncthreads();             // previous chunk fully consumed
        // pure-copy staging (no arithmetic; image prebuilt by repack_k)
        {
            const uint4* g4 = reinterpret_cast<const uint4*>(ws + ch * CHUNK_U);
            #pragma unroll
            for (int i = 0; i < 6; ++i) {
                int idx = t + i * BT;
                if (idx < CHUNK_U / 4) ldsb[idx] = g4[idx];
            }
        }
        __syncthreads();             // chunk visible

        #pragma unroll
        for (int ih = 0; ih < 2; ++ih) {
            const unsigned cbr = (unsigned)(bits >> (ch * 16 + ih * 8)) & 0xFFu;

            #pragma unroll 2
            for (int qq = 0; qq < 8; ++qq) {
                const int j    = ih ? 7 - qq : qq;      // snake column
                const int slot = ih * 8 + j;

                const unsigned* Tb = Tl + (slot * 12 + sub * 3) * 24;
                const float*   VEb = VE + (slot * 4 + sub) * 8;

                h2v hvh0, hvh1, hvh2;
                if (qq == 0) {
                    // row-boundary bypass: this column was written last step
                    // of the previous row; its value is the carried hhp.
                    if (ch == 0 && ih == 0) {
                        H2U z; z.u = 0u;
                        hvh0 = z.h; hvh1 = z.h; hvh2 = z.h;   // bottom boundary
                    } else {
                        hvh0 = hhp0; hvh1 = hhp1; hvh2 = hhp2;
                    }
                    #pragma unroll
                    for (int o = 0; o < 6; ++o) hh[o] = 1.f;  // left boundary
                    H2U one; one.u = 0x3C003C00u;
                    hhp0 = one.h; hhp1 = one.h; hhp2 = one.h;
                } else {
                    uint4 hvu = *reinterpret_cast<const uint4*>(vsm + j * 256 + s * 4);
                    hvh0 = u2h(hvu.x); hvh1 = u2h(hvu.y); hvh2 = u2h(hvu.z);
                }

                float4 ve0 = *reinterpret_cast<const float4*>(VEb);     // v0 v1 v2 e0^2
                float2 ve1 = *reinterpret_cast<const float2*>(VEb + 4); // e1^2 e2^2
                const float vv_[3] = { ve0.x, ve0.y, ve0.z };
                const float e2_[3] = { ve0.w, ve1.x, ve1.y };

                float acc[3];
                #pragma unroll
                for (int lr = 0; lr < 3; ++lr) {
                    const unsigned* Tr = Tb + lr * 24;
                    uint4 tA = *reinterpret_cast<const uint4*>(Tr);      // T 0..3
                    uint4 tB = *reinterpret_cast<const uint4*>(Tr + 4);  // T 4..7
                    uint4 tC = *reinterpret_cast<const uint4*>(Tr + 8);  // T 8..11
                    uint4 tD = *reinterpret_cast<const uint4*>(Tr + 12); // T 12..15
                    uint4 tE = *reinterpret_cast<const uint4*>(Tr + 16); // T16 T17 mh0 mh1
                    uint4 tF = *reinterpret_cast<const uint4*>(Tr + 20); // mh2 mv0 mv1 mv2
                    const unsigned tw[18] = {tA.x,tA.y,tA.z,tA.w, tB.x,tB.y,tB.z,tB.w,
                                             tC.x,tC.y,tC.z,tC.w, tD.x,tD.y,tD.z,tD.w,
                                             tE.x,tE.y};
                    float sc[6];
                    #pragma unroll
                    for (int c = 0; c < 6; ++c)
                        sc[c] = fdot2u(tw[c*3+0], hvh0,
                                fdot2u(tw[c*3+1], hvh1,
                                fdot2u(tw[c*3+2], hvh2, 0.f)));

                    float ta = fmaf(sc[0], hh[0], fmaf(sc[2], hh[2], sc[4]*hh[4]));
                    float tb = fmaf(sc[1], hh[1], fmaf(sc[3], hh[3], sc[5]*hh[5]));
                    float md = fdot2u(tE.z, hhp0, fdot2u(tE.w, hhp1,
                               fdot2u(tF.x, hhp2, vv_[lr])));   // diag-folded + V seed
                    float nd = fdot2u(tF.y, hvh0, fdot2u(tF.z, hvh1,
                               fdot2u(tF.w, hvh2, 0.f)));       // diag-folded
                    acc[lr] = (ta + tb) + (md + nd);
                }

                // 4-lane reductions via DPP quad_perm
                float q0_ = acc[0]*acc[0], q1_ = acc[1]*acc[1], q2_ = acc[2]*acc[2];
                float ssl = (q0_ + q1_) + q2_;
                float pq  = fmaf(e2_[0], q0_, fmaf(e2_[1], q1_, e2_[2] * q2_));
                float s1  = ssl + DPPF(ssl, QP_XOR1);
                float ssq = s1 + DPPF(s1, QP_XOR2);
                float p1  = pq + DPPF(pq, QP_XOR1);
                float px  = DPPF(p1, QP_XOR2);
                const float inv = FAST_RSQ(ssq + 1e-12f);

                const int sel = (cbr >> qq) & 1;
                const float qsel = (mya == sel) ? p1 : px;
                amp2 *= qsel * FAST_RCP(p1 + px);

                float an0 = acc[0] * inv, an1 = acc[1] * inv, an2 = acc[2] * inv;
                float sw0 = DPPF(an0, QP_XOR2);
                float sw1 = DPPF(an1, QP_XOR2);
                float sw2 = DPPF(an2, QP_XOR2);
                an0 = sel ? sw0 : an0;
                an1 = sel ? sw1 : an1;
                an2 = sel ? sw2 : an2;
                hh[0] = DPPF(an0, QP_BC0); hh[3] = DPPF(an0, QP_BC1);
                hh[1] = DPPF(an1, QP_BC0); hh[4] = DPPF(an1, QP_BC1);
                hh[2] = DPPF(an2, QP_BC0); hh[5] = DPPF(an2, QP_BC1);
                hhp0 = pack2(hh[0], hh[1]);
                hhp1 = pack2(hh[2], hh[3]);
                hhp2 = pack2(hh[4], hh[5]);

                // phase via packed W dot2s (+ C seed)
                uint4 wv = Wl[slot];
                phi = fdot2u(wv.x, hhp0, fdot2u(wv.y, hhp1,
                      fdot2u(wv.z, hhp2, __uint_as_float(wv.w) + phi)));

                // vs write (skipped at qq==7: superseded by next row's qq==0)
                if (sub == 0 && qq != 7) {
                    *reinterpret_cast<uint4*>(vsm + j * 256 + s * 4) =
                        make_uint4(h2u(hhp0), h2u(hhp1), h2u(hhp2), 0u);
                }
            }
        }
    }

    if (sub == 0 && valid) {
        const float amp = sqrtf(amp2);
        if (writeImag) {
            out[2 * b + 0] = amp * cosf(phi);
            out[2 * b + 1] = amp * sinf(phi);
        } else {
            out[b] = amp * cosf(phi);
        }
    }
}

// ---------- fallback: r16 kernel (in-kernel staging) ------------------------
__global__ __launch_bounds__(BT, 1) void mps_rnn16fb(
    const float* __restrict__ Mh, const float* __restrict__ Mv,
    const float* __restrict__ Vp, const float* __restrict__ Tp,
    const float* __restrict__ Wp, const float* __restrict__ Cp,
    const float* __restrict__ Ep, const int* __restrict__ X,
    float* __restrict__ out, int Bn, int writeImag)
{
    __shared__ unsigned Tl[16 * 12 * 24];
    __shared__ float    VE [16 * 4 * 8];
    __shared__ uint4    Wl [16];
    __shared__ unsigned vsm[8 * 64 * 4];

    const int t   = threadIdx.x;
    const int sub = t & 3;
    const int s   = t >> 2;
    int b = blockIdx.x * SPB + s;
    const bool valid = (b < Bn);
    if (!valid) b = Bn - 1;

    unsigned long long bits;
    {
        const int4* xr = reinterpret_cast<const int4*>(X + (size_t)b * NQ + sub * 16);
        unsigned long long part = 0ull;
        #pragma unroll
        for (int q = 0; q < 4; ++q) {
            int4 v = xr[q];
            part |= (unsigned long long)(v.x & 1) << (4 * q + 0);
            part |= (unsigned long long)(v.y & 1) << (4 * q + 1);
            part |= (unsigned long long)(v.z & 1) << (4 * q + 2);
            part |= (unsigned long long)(v.w & 1) << (4 * q + 3);
        }
        bits = part << (16 * sub);
        bits |= __shfl_xor(bits, 1, 64);
        bits |= __shfl_xor(bits, 2, 64);
    }
    for (int u = t; u < 8 * 64 * 4; u += BT) vsm[u] = 0u;
    const int mya = sub >> 1;
    float hh[6];
    h2v hhp0, hhp1, hhp2;
    float amp2 = 1.f, phi = 0.f;

    for (int ch = 0; ch < 4; ++ch) {
        __syncthreads();
        {
            const float2* gT = reinterpret_cast<const float2*>(Tp + ch * 6912);
            for (int p = t; p < 3456; p += BT) {
                int site = p / 216, rr = p - site * 216;
                int row = rr / 18,  w  = rr - row * 18;
                float2 v = gT[p];
                H2U hu; hu.hh = __floats2half2_rn(v.x, v.y);
                Tl[(site * 12 + row) * 24 + w] = hu.u;
            }
            const float2* gH = reinterpret_cast<const float2*>(Mh + ch * 1152);
            const float2* gV = reinterpret_cast<const float2*>(Mv + ch * 1152);
            for (int p = t; p < 576; p += BT) {
                int site = p / 36, rr = p - site * 36;
                int row = rr / 3,  w  = rr - row * 3;
                int o_r = row - ((row >= 6) ? 6 : 0);
                float2 vh = gH[p], vv2 = gV[p];
                if ((o_r >> 1) == w) {
                    if (o_r & 1) { vh.y += 1.f; vv2.y += 1.f; }
                    else         { vh.x += 1.f; vv2.x += 1.f; }
                }
                H2U a; a.hh = __floats2half2_rn(vh.x, vh.y);
                H2U c; c.hh = __floats2half2_rn(vv2.x, vv2.y);
                Tl[(site * 12 + row) * 24 + 18 + w] = a.u;
                Tl[(site * 12 + row) * 24 + 21 + w] = c.u;
            }
            if (t < 192) {
                int site = t / 12, q = t - site * 12;
                int sb = q / 3,    c = q - sb * 3;
                VE[(site * 4 + sb) * 8 + c] = Vp[ch * 192 + t];
                float e = Ep[ch * 96 + site * 6 + (sb & 1) * 3 + c];
                VE[(site * 4 + sb) * 8 + 3 + c] = e * e;
            } else if (t < 208) {
                int site = t - 192;
                const float2* gw = reinterpret_cast<const float2*>(Wp) + ch * 48 + site * 3;
                float2 w01 = gw[0], w23 = gw[1], w45 = gw[2];
                H2U u0, u1, u2;
                u0.hh = __floats2half2_rn(w01.x, w01.y);
                u1.hh = __floats2half2_rn(w23.x, w23.y);
                u2.hh = __floats2half2_rn(w45.x, w45.y);
                Wl[site] = make_uint4(u0.u, u1.u, u2.u,
                                      __float_as_uint(Cp[ch * 16 + site]));
            }
        }
        __syncthreads();

        #pragma unroll
        for (int ih = 0; ih < 2; ++ih) {
            const unsigned cbr = (unsigned)(bits >> (ch * 16 + ih * 8)) & 0xFFu;
            #pragma unroll 2
            for (int qq = 0; qq < 8; ++qq) {
                const int j    = ih ? 7 - qq : qq;
                const int slot = ih * 8 + j;
                const unsigned* Tb = Tl + (slot * 12 + sub * 3) * 24;
                const float*   VEb = VE + (slot * 4 + sub) * 8;
                if (qq == 0) {
                    #pragma unroll
                    for (int o = 0; o < 6; ++o) hh[o] = 1.f;
                    H2U one; one.u = 0x3C003C00u;
                    hhp0 = one.h; hhp1 = one.h; hhp2 = one.h;
                }
                uint4 hvu = *reinterpret_cast<const uint4*>(vsm + j * 256 + s * 4);
                const h2v hvh0 = u2h(hvu.x);
                const h2v hvh1 = u2h(hvu.y);
                const h2v hvh2 = u2h(hvu.z);
                float4 ve0 = *reinterpret_cast<const float4*>(VEb);
                float2 ve1 = *reinterpret_cast<const float2*>(VEb + 4);
                const float vv_[3] = { ve0.x, ve0.y, ve0.z };
                const float e2_[3] = { ve0.w, ve1.x, ve1.y };
                float acc[3];
                #pragma unroll
                for (int lr = 0; lr < 3; ++lr) {
                    const unsigned* Tr = Tb + lr * 24;
                    uint4 tA = *reinterpret_cast<const uint4*>(Tr);
                    uint4 tB = *reinterpret_cast<const uint4*>(Tr + 4);
                    uint4 tC = *reinterpret_cast<const uint4*>(Tr + 8);
                    uint4 tD = *reinterpret_cast<const uint4*>(Tr + 12);
                    uint4 tE = *reinterpret_cast<const uint4*>(Tr + 16);
                    uint4 tF = *reinterpret_cast<const uint4*>(Tr + 20);
                    const unsigned tw[18] = {tA.x,tA.y,tA.z,tA.w, tB.x,tB.y,tB.z,tB.w,
                                             tC.x,tC.y,tC.z,tC.w, tD.x,tD.y,tD.z,tD.w,
                                             tE.x,tE.y};
                    float sc[6];
                    #pragma unroll
                    for (int c = 0; c < 6; ++c)
                        sc[c] = fdot2u(tw[c*3+0], hvh0,
                                fdot2u(tw[c*3+1], hvh1,
                                fdot2u(tw[c*3+2], hvh2, 0.f)));
                    float ta = fmaf(sc[0], hh[0], fmaf(sc[2], hh[2], sc[4]*hh[4]));
                    float tb = fmaf(sc[1], hh[1], fmaf(sc[3], hh[3], sc[5]*hh[5]));
                    float md = fdot2u(tE.z, hhp0, fdot2u(tE.w, hhp1,
                               fdot2u(tF.x, hhp2, vv_[lr])));
                    float nd = fdot2u(tF.y, hvh0, fdot2u(tF.z, hvh1,
                               fdot2u(tF.w, hvh2, 0.f)));
                    acc[lr] = (ta + tb) + (md + nd);
                }
                float q0_ = acc[0]*acc[0], q1_ = acc[1]*acc[1], q2_ = acc[2]*acc[2];
                float ssl = (q0_ + q1_) + q2_;
                float pq  = fmaf(e2_[0], q0_, fmaf(e2_[1], q1_, e2_[2] * q2_));
                float s1  = ssl + DPPF(ssl, QP_XOR1);
                float ssq = s1 + DPPF(s1, QP_XOR2);
                float p1  = pq + DPPF(pq, QP_XOR1);
                float px  = DPPF(p1, QP_XOR2);
                const float inv = FAST_RSQ(ssq + 1e-12f);
                const int sel = (cbr >> qq) & 1;
                const float qsel = (mya == sel) ? p1 : px;
                amp2 *= qsel * FAST_RCP(p1 + px);
                float an0 = acc[0] * inv, an1 = acc[1] * inv, an2 = acc[2] * inv;
                float sw0 = DPPF(an0, QP_XOR2);
                float sw1 = DPPF(an1, QP_XOR2);
                float sw2 = DPPF(an2, QP_XOR2);
                an0 = sel ? sw0 : an0;
                an1 = sel ? sw1 : an1;
                an2 = sel ? sw2 : an2;
                hh[0] = DPPF(an0, QP_BC0); hh[3] = DPPF(an0, QP_BC1);
                hh[1] = DPPF(an1, QP_BC0); hh[4] = DPPF(an1, QP_BC1);
                hh[2] = DPPF(an2, QP_BC0); hh[5] = DPPF(an2, QP_BC1);
                hhp0 = pack2(hh[0], hh[1]);
                hhp1 = pack2(hh[2], hh[3]);
                hhp2 = pack2(hh[4], hh[5]);
                uint4 wv = Wl[slot];
                phi = fdot2u(wv.x, hhp0, fdot2u(wv.y, hhp1,
                      fdot2u(wv.z, hhp2, __uint_as_float(wv.w) + phi)));
                if (sub == 0) {
                    *reinterpret_cast<uint4*>(vsm + j * 256 + s * 4) =
                        make_uint4(h2u(hhp0), h2u(hhp1), h2u(hhp2), 0u);
                }
            }
        }
    }

    if (sub == 0 && valid) {
        const float amp = sqrtf(amp2);
        if (writeImag) {
            out[2 * b + 0] = amp * cosf(phi);
            out[2 * b + 1] = amp * sinf(phi);
        } else {
            out[b] = amp * cosf(phi);
        }
    }
}

extern "C" void kernel_launch(void* const* d_in, const int* in_sizes, int n_in,
                              void* d_out, int out_size, void* d_ws, size_t ws_size,
                              hipStream_t stream) {
    const float* Mh = (const float*)d_in[0];
    const float* Mv = (const float*)d_in[1];
    const float* Vp = (const float*)d_in[2];
    const float* Tp = (const float*)d_in[3];
    const float* Wp = (const float*)d_in[4];
    const float* Cp = (const float*)d_in[5];
    const float* Ep = (const float*)d_in[6];
    const int*   X  = (const int*)d_in[7];
    float* out = (float*)d_out;

    const int Bn = in_sizes[7] / NQ;                 // 32768
    const int writeImag = (out_size >= 2 * Bn) ? 1 : 0;
    const int grid = (Bn + SPB - 1) / SPB;           // 512 blocks of 256 threads

    const size_t need = (size_t)4 * CHUNK_U * sizeof(unsigned);  // 82944 B
    if (ws_size >= need) {
        repack_k<<<4, BT, 0, stream>>>(Mh, Mv, Vp, Tp, Wp, Cp, Ep,
                                       (unsigned*)d_ws);
        mps_rnn24<<<grid, BT, 0, stream>>>((const unsigned*)d_ws, X, out,
                                           Bn, writeImag);
    } else {
        mps_rnn16fb<<<grid, BT, 0, stream>>>(Mh, Mv, Vp, Tp, Wp, Cp, Ep, X,
                                             out, Bn, writeImag);
    }
}